// Round 4
// baseline (694.969 us; speedup 1.0000x reference)
//
#include <hip/hip_runtime.h>
#include <hip/hip_fp16.h>
#include <cstddef>

// StackLSTM: T=64, B=128, H=256, L=2.  ops∈{0,1} => stack never pops:
// top-of-stack = h(last push step), maintained by gated update.
//
// Round-11: SINGLE block per (bg,hg) computing L0 step t and L1 step t-1
// per iteration (L1 lags one step). One combined tagged poll per iteration
// (h0(t-1) always, h1(t-2) gated) serves both layers -> ONE exposed RT +
// 2 barriers per step. cell0 runs on waves 0-1, cell1 on waves 2-3 in
// parallel. Grid = 256 blocks = 1 block/CU: co-residency structurally safe
// (r10's 31ms outlier = timeout under broken 512-block residency).
//  * Xg (x@Wih0 + both layer-0 biases, exact fp32) precomputed in an
//    in-kernel prologue into ws (block-local slice, ~30us, grid-parallel);
//    main loop loads 4 floats/thread at iteration top, hidden under poll.
//  * Exchange = depth-4 tagged ring (tag=step+1 disambiguates reuse; skew
//    between bg-peers is <=1 iter because everyone polls everyone each
//    step). ws use: 32MB Xg + 2x0.5MB rings = 33MB <= proven 35.1MB budget.
//  * Keeps: swizzled LDS h-tiles, push-gated a0r/a1q caches, f16 exchange.
#define TT 64
#define BB 128
#define HH 256
#define G4 1024
#define BLK 256
#define NBG 16
#define RING 4

// ws float-slot offsets
#define OFF_XG  0u         // [bg*16+hg][64 t][8 b][64 lc] f32 = 8,388,608
#define OFF_HX0 8388608u   // u64 [4 ring][16 bg][8 b][128 k2] = 131,072 fl
#define OFF_HX1 8519680u   // same
// total 8,650,752 floats = 33.0 MB (< r7-r9's 8,781,824 proven budget)

__device__ __forceinline__ float sigf(float x) { return 1.0f / (1.0f + expf(-x)); }

typedef _Float16 h2v __attribute__((ext_vector_type(2)));

__device__ __forceinline__ float dot2acc(unsigned w, unsigned h, float acc) {
#if __has_builtin(__builtin_amdgcn_fdot2)
  return __builtin_amdgcn_fdot2(__builtin_bit_cast(h2v, w),
                                __builtin_bit_cast(h2v, h), acc, false);
#else
  __half2 wv = *(__half2*)&w, hv = *(__half2*)&h;
  float2 wf = __half22float2(wv), hf = __half22float2(hv);
  return fmaf(wf.x, hf.x, fmaf(wf.y, hf.y, acc));
#endif
}

__device__ __forceinline__ unsigned packh2(float e, float o) {
  return (unsigned)__half_as_ushort(__float2half(e)) |
         ((unsigned)__half_as_ushort(__float2half(o)) << 16);
}

// swizzled word offset in [8 b][144] h-buffers: 16-word row per kq staggered
// by (kq>>1)*4 words -> row starts hit banks {0,16,4,20,8,24,12,28}.
__device__ __forceinline__ int hsw8(int b, int k2) {
  return b * 144 + k2 + ((k2 >> 5) << 2);
}

__global__ void __launch_bounds__(BLK, 1)
seq11(const float* __restrict__ x,
      const int* __restrict__ ops,
      const float* __restrict__ W_ih,
      const float* __restrict__ W_hh,
      const float* __restrict__ b_ih,
      const float* __restrict__ b_hh,
      float* __restrict__ ws,
      float* __restrict__ out) {
  const int bg = blockIdx.x & 15;     // batch group (8 b)
  const int hg = blockIdx.x >> 4;     // 0..15 (16 h-dims)
  const int tid = threadIdx.x;
  const int kq = tid & 7;             // k-slice: k2 in [kq*16, kq*16+16)
  const int c2 = tid >> 3;            // 0..31: gate cols {c2*2, c2*2+1}

  __shared__ __align__(16) unsigned smh[3 * 1152];  // h0c | hp0 | hp1 (swz)
  __shared__ __align__(16) float gatA[8 * 68];      // stride 68: bank-spread
  __shared__ __align__(16) float gatB[8 * 68];
  __shared__ int opsA[TT * 8];

  unsigned* h0c = smh;            // raw h0(t-1) (f16x2)
  unsigned* hp0 = smh + 1152;     // gated h0 stack top
  unsigned* hp1 = smh + 2304;     // gated h1 stack top

  for (int i = tid; i < TT * 8; i += BLK)
    opsA[i] = ops[(i >> 3) * BB + bg * 8 + (i & 7)];

  float* __restrict__ Xg = ws + OFF_XG + (size_t)(bg * 16 + hg) * 32768;
  unsigned long long* __restrict__ Hx0 = (unsigned long long*)(ws + OFF_HX0);
  unsigned long long* __restrict__ Hx1 = (unsigned long long*)(ws + OFF_HX1);

  // ---------------- prologue: Xg[t][b][lc] = x(t,b)@Wih0 + bih0 + bhh0 ----
  {
    float wx0[64];    // 2 cols x 32-k slice, fp32 (exact)
    float pb0[2];
#pragma unroll
    for (int j = 0; j < 2; ++j) {
      const int lc = c2 * 2 + j;
      const int g = ((lc >> 4) << 8) + hg * 16 + (lc & 15);
      const float* pw = W_ih + (size_t)g * HH + kq * 32;
#pragma unroll
      for (int i = 0; i < 32; ++i) wx0[j * 32 + i] = pw[i];
      pb0[j] = b_ih[g] + b_hh[g];
    }
    float* xs = (float*)smh;      // [8 b][288] skewed fp32 x (aliases smh)
    for (int t = 0; t < TT; ++t) {
      const float4* xsrc = (const float4*)(x + ((size_t)t * BB + bg * 8) * HH);
      const float4 va = xsrc[tid];
      const float4 vb = xsrc[tid + 256];
      __syncthreads();            // xs free (previous t's reads done)
      {
        const int b0_ = tid >> 6, k40 = tid & 63;
        *(float4*)&xs[b0_ * 288 + (k40 >> 3) * 36 + (k40 & 7) * 4] = va;
        const int f4 = tid + 256;
        const int b1_ = f4 >> 6, k41 = f4 & 63;
        *(float4*)&xs[b1_ * 288 + (k41 >> 3) * 36 + (k41 & 7) * 4] = vb;
      }
      __syncthreads();
#pragma unroll
      for (int b = 0; b < 8; ++b) {
        const float* xb = &xs[b * 288 + kq * 36];
        float s0 = 0.f, s1 = 0.f;
#pragma unroll
        for (int k = 0; k < 32; k += 4) {
          const float4 xv = *(const float4*)&xb[k];
          s0 = fmaf(wx0[k], xv.x, s0);
          s0 = fmaf(wx0[k + 1], xv.y, s0);
          s0 = fmaf(wx0[k + 2], xv.z, s0);
          s0 = fmaf(wx0[k + 3], xv.w, s0);
          s1 = fmaf(wx0[32 + k], xv.x, s1);
          s1 = fmaf(wx0[32 + k + 1], xv.y, s1);
          s1 = fmaf(wx0[32 + k + 2], xv.z, s1);
          s1 = fmaf(wx0[32 + k + 3], xv.w, s1);
        }
#pragma unroll
        for (int m = 1; m <= 4; m <<= 1) {
          s0 += __shfl_xor(s0, m, 64);
          s1 += __shfl_xor(s1, m, 64);
        }
        if (kq == 0)
          *(float2*)&Xg[(size_t)t * 512 + b * 64 + c2 * 2] =
              make_float2(s0 + pb0[0], s1 + pb0[1]);
      }
    }
  }

  // ---- recurrence weights -> VGPRs (f16 pairs) ----
  unsigned wr0[32], wr1[32], wr2[32];
  float bias1r[2];
#pragma unroll
  for (int j = 0; j < 2; ++j) {
    const int lc = c2 * 2 + j;
    const int g = ((lc >> 4) << 8) + hg * 16 + (lc & 15);
    const float* p0 = W_hh + (size_t)g * HH + kq * 32;
    const float* p1 = W_ih + (size_t)G4 * HH + (size_t)g * HH + kq * 32;
    const float* p2 = W_hh + (size_t)G4 * HH + (size_t)g * HH + kq * 32;
#pragma unroll
    for (int i = 0; i < 16; ++i) {
      wr0[j * 16 + i] = packh2(p0[2 * i], p0[2 * i + 1]);
      wr1[j * 16 + i] = packh2(p1[2 * i], p1[2 * i + 1]);
      wr2[j * 16 + i] = packh2(p2[2 * i], p2[2 * i + 1]);
    }
    bias1r[j] = b_ih[G4 + g] + b_hh[G4 + g];
  }

  const int pb = tid >> 5;            // polled batch
  const int pk2 = (tid & 31) * 4;     // polled k2 base (4 words, 32B)
  float a0r[8][2] = {};               // cached Whh0.hp0 (post-butterfly)
  float a1q[8][2] = {};               // cached Whh1.hp1
  float cp0 = 0.f, cp1 = 0.f;         // cell states (waves 0-1 / 2-3)

  // iteration t: L0 computes step t (t<TT); L1 computes step t-1 (t>=1)
  for (int t = 0; t <= TT; ++t) {
    // ---- early Xg load (used in cell0 after B1; hidden under poll) ----
    float xg0 = 0.f, xg1 = 0.f, xg2 = 0.f, xg3 = 0.f;
    if (t < TT && tid < 128) {
      const int b = tid >> 4, r = tid & 15;
      const float* xp = &Xg[(size_t)t * 512 + b * 64 + r];
      xg0 = xp[0]; xg1 = xp[16]; xg2 = xp[32]; xg3 = xp[48];
    }
    // ---- combined tagged poll: h0(t-1) always, h1(t-2) gated ----
    if (t >= 1) {
      const unsigned long long* sp0 =
          Hx0 + ((size_t)((t - 1) & (RING - 1)) * NBG + bg) * 1024;
      const unsigned tag0 = (unsigned)t;
      const bool need1 = (t >= 2) && (opsA[(t - 2) * 8 + pb] != 0);
      const unsigned long long* sp1 =
          Hx1 + ((size_t)((t >= 2 ? t - 2 : 0) & (RING - 1)) * NBG + bg) * 1024;
      const unsigned tag1 = (unsigned)(t - 1);
      unsigned long long v[4], w[4] = {0, 0, 0, 0};
      bool dv[4] = {false, false, false, false};
      bool dw[4] = {!need1, !need1, !need1, !need1};
      int spins = 0;
      for (;;) {
#pragma unroll
        for (int i = 0; i < 4; ++i) {
          if (!dv[i]) v[i] = __hip_atomic_load(sp0 + tid * 4 + i, __ATOMIC_RELAXED,
                                               __HIP_MEMORY_SCOPE_AGENT);
          if (!dw[i]) w[i] = __hip_atomic_load(sp1 + tid * 4 + i, __ATOMIC_RELAXED,
                                               __HIP_MEMORY_SCOPE_AGENT);
        }
        bool all = true;
#pragma unroll
        for (int i = 0; i < 4; ++i) {
          dv[i] = dv[i] || ((unsigned)v[i] == tag0);
          dw[i] = dw[i] || ((unsigned)w[i] == tag1);
          all = all && dv[i] && dw[i];
        }
        if (all) break;
        if (++spins > (1 << 18)) break;  // fail loudly instead of hanging
        if (spins > 2) __builtin_amdgcn_s_sleep(1);
      }
      const int sw = hsw8(pb, pk2);
      const uint4 pay =
          make_uint4((unsigned)(v[0] >> 32), (unsigned)(v[1] >> 32),
                     (unsigned)(v[2] >> 32), (unsigned)(v[3] >> 32));
      *(uint4*)&h0c[sw] = pay;
      if (opsA[(t - 1) * 8 + pb]) *(uint4*)&hp0[sw] = pay;
      if (need1)
        *(uint4*)&hp1[sw] =
            make_uint4((unsigned)(w[0] >> 32), (unsigned)(w[1] >> 32),
                       (unsigned)(w[2] >> 32), (unsigned)(w[3] >> 32));
    }
    __syncthreads();  // B0: h0c/hp0/hp1 ready

    // ---- L0 gated dots: refresh a0r where op[t-1]=1 ----
    if (t >= 1 && t < TT) {
#pragma unroll
      for (int b = 0; b < 8; ++b) {
        if (opsA[(t - 1) * 8 + b]) {   // uniform branch
          const unsigned* hb = &hp0[b * 144 + kq * 16 + ((kq >> 1) << 2)];
          const uint4 x0 = *(const uint4*)(hb + 0);
          const uint4 x1 = *(const uint4*)(hb + 4);
          const uint4 x2 = *(const uint4*)(hb + 8);
          const uint4 x3 = *(const uint4*)(hb + 12);
          const unsigned hh[16] = {x0.x, x0.y, x0.z, x0.w, x1.x, x1.y, x1.z, x1.w,
                                   x2.x, x2.y, x2.z, x2.w, x3.x, x3.y, x3.z, x3.w};
          float s0 = 0.f, s1 = 0.f;
#pragma unroll
          for (int i = 0; i < 16; ++i) {
            s0 = dot2acc(wr0[i], hh[i], s0);
            s1 = dot2acc(wr0[16 + i], hh[i], s1);
          }
#pragma unroll
          for (int m = 1; m <= 4; m <<= 1) {
            s0 += __shfl_xor(s0, m, 64);
            s1 += __shfl_xor(s1, m, 64);
          }
          a0r[b][0] = s0; a0r[b][1] = s1;
        }
      }
    }
    // ---- L1 dots (step t-1): wr1.h0c always; wr2.hp1 gated ----
    if (t >= 1) {
#pragma unroll
      for (int b = 0; b < 8; ++b) {
        const unsigned* cb = &h0c[b * 144 + kq * 16 + ((kq >> 1) << 2)];
        const uint4 c0 = *(const uint4*)(cb + 0);
        const uint4 c1 = *(const uint4*)(cb + 4);
        const uint4 c2v = *(const uint4*)(cb + 8);
        const uint4 c3 = *(const uint4*)(cb + 12);
        const unsigned hc[16] = {c0.x, c0.y, c0.z, c0.w, c1.x, c1.y, c1.z, c1.w,
                                 c2v.x, c2v.y, c2v.z, c2v.w, c3.x, c3.y, c3.z, c3.w};
        float s0 = 0.f, s1 = 0.f;
#pragma unroll
        for (int i = 0; i < 16; ++i) {
          s0 = dot2acc(wr1[i], hc[i], s0);
          s1 = dot2acc(wr1[16 + i], hc[i], s1);
        }
        if (t >= 2 && opsA[(t - 2) * 8 + b]) {   // uniform branch
          const unsigned* qb = &hp1[b * 144 + kq * 16 + ((kq >> 1) << 2)];
          const uint4 q0 = *(const uint4*)(qb + 0);
          const uint4 q1 = *(const uint4*)(qb + 4);
          const uint4 q2 = *(const uint4*)(qb + 8);
          const uint4 q3 = *(const uint4*)(qb + 12);
          const unsigned hq[16] = {q0.x, q0.y, q0.z, q0.w, q1.x, q1.y, q1.z, q1.w,
                                   q2.x, q2.y, q2.z, q2.w, q3.x, q3.y, q3.z, q3.w};
          float t0 = 0.f, t1 = 0.f;
#pragma unroll
          for (int i = 0; i < 16; ++i) {
            t0 = dot2acc(wr2[i], hq[i], t0);
            t1 = dot2acc(wr2[16 + i], hq[i], t1);
          }
#pragma unroll
          for (int m = 1; m <= 4; m <<= 1) {
            t0 += __shfl_xor(t0, m, 64);
            t1 += __shfl_xor(t1, m, 64);
          }
          a1q[b][0] = t0; a1q[b][1] = t1;
        }
#pragma unroll
        for (int m = 1; m <= 4; m <<= 1) {
          s0 += __shfl_xor(s0, m, 64);
          s1 += __shfl_xor(s1, m, 64);
        }
        if (kq == 0)
          *(float2*)&gatB[b * 68 + c2 * 2] =
              make_float2(s0 + a1q[b][0] + bias1r[0],
                          s1 + a1q[b][1] + bias1r[1]);
      }
    }
    if (t < TT && kq == 0) {
#pragma unroll
      for (int b = 0; b < 8; ++b)
        *(float2*)&gatA[b * 68 + c2 * 2] = make_float2(a0r[b][0], a0r[b][1]);
    }
    __syncthreads();  // B1: gatA/gatB ready

    // ---- cells in parallel: cell0 on waves 0-1, cell1 on waves 2-3 ----
    if (tid < 128) {
      if (t < TT) {
        const int b = tid >> 4, r = tid & 15;
        const float* gt = &gatA[b * 68];
        const float ig = gt[r] + xg0,      fg = gt[16 + r] + xg1;
        const float gg = gt[32 + r] + xg2, og = gt[48 + r] + xg3;
        const float c = sigf(fg) * cp0 + sigf(ig) * tanhf(gg);
        const float h = sigf(og) * tanhf(c);
        if (opsA[t * 8 + b]) cp0 = c;
        const float ho = __shfl_xor(h, 1, 64);
        if (!(r & 1)) {
          const unsigned long long vv =
              (unsigned long long)(unsigned)(t + 1) |
              ((unsigned long long)packh2(h, ho) << 32);
          __hip_atomic_store(
              Hx0 + ((size_t)(t & (RING - 1)) * NBG + bg) * 1024 +
                  b * 128 + hg * 8 + (r >> 1),
              vv, __ATOMIC_RELAXED, __HIP_MEMORY_SCOPE_AGENT);
        }
      }
    } else if (t >= 1) {
      const int s = t - 1;
      const int b = (tid >> 4) & 7, r = tid & 15;
      const float* gt = &gatB[b * 68];
      const float ig = gt[r],      fg = gt[16 + r];
      const float gg = gt[32 + r], og = gt[48 + r];
      const float c = sigf(fg) * cp1 + sigf(ig) * tanhf(gg);
      const float h = sigf(og) * tanhf(c);
      const int op = opsA[s * 8 + b];
      if (op) cp1 = c;
      out[((size_t)s * BB + bg * 8 + b) * HH + hg * 16 + r] = h;
      const float ho = __shfl_xor(h, 1, 64);
      if (op && !(r & 1)) {  // consumers poll these words only when op=1
        const unsigned long long vv =
            (unsigned long long)(unsigned)(s + 1) |
            ((unsigned long long)packh2(h, ho) << 32);
        __hip_atomic_store(
            Hx1 + ((size_t)(s & (RING - 1)) * NBG + bg) * 1024 +
                b * 128 + hg * 8 + (r >> 1),
            vv, __ATOMIC_RELAXED, __HIP_MEMORY_SCOPE_AGENT);
      }
    }
    // no trailing barrier: B0/B1 of next iteration cover all LDS reuse
  }
}

// ---------------------------------------------------------------------------
extern "C" void kernel_launch(void* const* d_in, const int* in_sizes, int n_in,
                              void* d_out, int out_size, void* d_ws, size_t ws_size,
                              hipStream_t stream) {
  const float* x    = (const float*)d_in[0];
  const int*   ops  = (const int*)d_in[1];
  const float* W_ih = (const float*)d_in[2];
  const float* W_hh = (const float*)d_in[3];
  const float* b_ih = (const float*)d_in[4];
  const float* b_hh = (const float*)d_in[5];
  float* out = (float*)d_out;
  float* ws  = (float*)d_ws;

  seq11<<<256, BLK, 0, stream>>>(x, ops, W_ih, W_hh, b_ih, b_hh, ws, out);
}